// Round 8
// baseline (281.180 us; speedup 1.0000x reference)
//
#include <hip/hip_runtime.h>

// Problem constants
constexpr int NN  = 50000;   // nodes
constexpr int NE  = 400000;  // edges
constexpr int F0  = 128;     // input features
constexpr int F1  = 512;     // hidden features
constexpr int F2  = 250;     // output features
constexpr int MT64 = 782;    // M tiles of 64 (782*64 = 50048)
constexpr int SLOT = 64;     // fixed-capacity CSR stride (Poisson(8): P(deg>64)~1e-40)

typedef short  short8 __attribute__((ext_vector_type(8)));
typedef float  f32x4  __attribute__((ext_vector_type(4)));

__device__ inline unsigned short f2bf(float f) {
    union { float f; unsigned u; } v; v.f = f;
    unsigned u = v.u;
    return (unsigned short)((u + 0x7FFFu + ((u >> 16) & 1u)) >> 16);   // RNE
}
__device__ inline float bf2f(unsigned short h) {
    union { unsigned u; float f; } v; v.u = ((unsigned)h) << 16;
    return v.f;
}
__device__ inline float bflo(unsigned u) {
    union { unsigned u; float f; } v; v.u = u << 16; return v.f;
}
__device__ inline float bfhi(unsigned u) {
    union { unsigned u; float f; } v; v.u = u & 0xFFFF0000u; return v.f;
}

// ========= CSR build: fused hist+bucket into fixed-stride slots =========
// cnt[d] ends as degree; slot[d*SLOT + i] = src of i-th incoming edge.
__global__ void k_build(const int4* __restrict__ src4, const int4* __restrict__ dst4,
                        int* __restrict__ cnt, int* __restrict__ slot) {
    int t = blockIdx.x * 256 + threadIdx.x;        // NE/4
    if (t >= NE / 4) return;
    int4 s = src4[t];
    int4 d = dst4[t];
    int p;
    p = atomicAdd(&cnt[d.x], 1); if (p < SLOT) slot[d.x * SLOT + p] = s.x;
    p = atomicAdd(&cnt[d.y], 1); if (p < SLOT) slot[d.y * SLOT + p] = s.y;
    p = atomicAdd(&cnt[d.z], 1); if (p < SLOT) slot[d.z * SLOT + p] = s.z;
    p = atomicAdd(&cnt[d.w], 1); if (p < SLOT) slot[d.w * SLOT + p] = s.w;
}

// ========= fused prep: xs = bf16(rsqrt(cnt+1)*x), W1t, W2t =========
__global__ __launch_bounds__(256) void k_prep(
        const float4* __restrict__ x4, const int* __restrict__ cnt,
        ushort4* __restrict__ xs,
        const float* __restrict__ W1, unsigned short* __restrict__ w1t,
        const float* __restrict__ W2, unsigned short* __restrict__ w2t) {
    int b = blockIdx.x;
    if (b < 6250) {                                // NN*32 = 1,600,000 float4s
        int t = b * 256 + threadIdx.x;
        float dn = rsqrtf((float)cnt[t >> 5] + 1.0f);
        float4 v = x4[t];
        ushort4 o;
        o.x = f2bf(dn * v.x); o.y = f2bf(dn * v.y);
        o.z = f2bf(dn * v.z); o.w = f2bf(dn * v.w);
        xs[t] = o;
    } else if (b < 6250 + 256) {                   // W1 [128,512] -> [512,128]
        int t = (b - 6250) * 256 + threadIdx.x;
        int n = t >> 7, k = t & 127;
        w1t[t] = f2bf(W1[k * F1 + n]);
    } else {                                       // W2 [512,250] -> [256,512], pad
        int t = (b - 6506) * 256 + threadIdx.x;
        int n = t >> 9, k = t & 511;
        w2t[t] = (n < F2) ? f2bf(W2[k * F2 + n]) : (unsigned short)0;
    }
}

// ========= fused layer 1: gather 64 node rows into LDS A-tile, then =========
// ========= single-shot K=128 MFMA GEMM -> h1 = relu(agg1*W1 + b1)  =========
// 16-slot XOR swizzle on both LDS tiles: chunk q of row m holds global chunk
// q^(m&15) -> frag ds_read_b128s are 2-way (free, m136).
__global__ __launch_bounds__(256) void k_fused1(
        const unsigned int* __restrict__ xs, const int* __restrict__ slot,
        const int* __restrict__ cnt, const unsigned short* __restrict__ Bt,
        const float* __restrict__ bias, unsigned short* __restrict__ C)
{
    __shared__ unsigned short As[64 * 128];    // 16 KB (gathered A-tile)
    __shared__ unsigned short Bs[128 * 128];   // 32 KB (one 128-col W1t chunk)
    unsigned int* As32 = (unsigned int*)As;

    const int tid = threadIdx.x;
    const int wv = tid >> 6, ln = tid & 63;
    const int m0 = blockIdx.x * 64;
    const int wy = wv >> 1, wx = wv & 1;
    const int lane15 = ln & 15, quad = ln >> 4;

    // ---- phase 1: each wave gathers 16 nodes into As (swizzled) ----
    const int qch = ln >> 2;                   // k-chunk (8 halfwords) of this lane
    const int cu  = ln & 3;                    // uint within chunk
    for (int i = 0; i < 16; ++i) {
        int m = wv * 16 + i;
        int n = m0 + m;
        int nc = n < NN ? n : NN - 1;
        int deg = cnt[nc]; if (deg > SLOT) deg = SLOT;
        float dn = rsqrtf((float)deg + 1.0f);
        const int* sl = slot + nc * SLOT;
        unsigned a = xs[(size_t)nc * 64 + ln];
        float s0 = bflo(a), s1 = bfhi(a);
        int j = 0;
        for (; j + 8 <= deg; j += 8) {
            int i0 = sl[j],     i1 = sl[j + 1], i2 = sl[j + 2], i3 = sl[j + 3];
            int i4 = sl[j + 4], i5 = sl[j + 5], i6 = sl[j + 6], i7 = sl[j + 7];
            unsigned v0 = xs[(size_t)i0 * 64 + ln];
            unsigned v1 = xs[(size_t)i1 * 64 + ln];
            unsigned v2 = xs[(size_t)i2 * 64 + ln];
            unsigned v3 = xs[(size_t)i3 * 64 + ln];
            unsigned v4 = xs[(size_t)i4 * 64 + ln];
            unsigned v5 = xs[(size_t)i5 * 64 + ln];
            unsigned v6 = xs[(size_t)i6 * 64 + ln];
            unsigned v7 = xs[(size_t)i7 * 64 + ln];
            s0 += bflo(v0) + bflo(v1) + bflo(v2) + bflo(v3)
                + bflo(v4) + bflo(v5) + bflo(v6) + bflo(v7);
            s1 += bfhi(v0) + bfhi(v1) + bfhi(v2) + bfhi(v3)
                + bfhi(v4) + bfhi(v5) + bfhi(v6) + bfhi(v7);
        }
        for (; j + 4 <= deg; j += 4) {
            int i0 = sl[j], i1 = sl[j + 1], i2 = sl[j + 2], i3 = sl[j + 3];
            unsigned v0 = xs[(size_t)i0 * 64 + ln];
            unsigned v1 = xs[(size_t)i1 * 64 + ln];
            unsigned v2 = xs[(size_t)i2 * 64 + ln];
            unsigned v3 = xs[(size_t)i3 * 64 + ln];
            s0 += bflo(v0) + bflo(v1) + bflo(v2) + bflo(v3);
            s1 += bfhi(v0) + bfhi(v1) + bfhi(v2) + bfhi(v3);
        }
        for (; j < deg; ++j) {
            unsigned v = xs[(size_t)sl[j] * 64 + ln];
            s0 += bflo(v); s1 += bfhi(v);
        }
        unsigned res = (n < NN)
            ? ((unsigned)f2bf(dn * s0) | ((unsigned)f2bf(dn * s1) << 16))
            : 0u;
        As32[m * 64 + ((qch ^ (m & 15)) << 2) + cu] = res;
    }
    __syncthreads();

    // ---- phase 2: 4 chunks of 128 output cols ----
    for (int nb = 0; nb < 4; ++nb) {
        const unsigned short* Bb = Bt + (size_t)nb * 128 * 128;
#pragma unroll
        for (int i = 0; i < 8; ++i) {              // stage 2048 16B chunks
            int c = i * 256 + tid;
            int nr = c >> 4, q = c & 15;
            int gq = q ^ (nr & 15);
            __builtin_amdgcn_global_load_lds(
                (const __attribute__((address_space(1))) void*)(Bb + (size_t)nr * 128 + gq * 8),
                (__attribute__((address_space(3))) void*)(Bs + (i * 4 + wv) * 512), 16, 0, 0);
        }
        __syncthreads();                           // Bs ready

        f32x4 acc[2][4];
#pragma unroll
        for (int fy = 0; fy < 2; ++fy)
#pragma unroll
            for (int fx = 0; fx < 4; ++fx)
                acc[fy][fx] = (f32x4)0.0f;

#pragma unroll
        for (int kk = 0; kk < 4; ++kk) {           // K = 4 x 32
            short8 af[2], bf[4];
#pragma unroll
            for (int f = 0; f < 2; ++f) {
                int mA = wy * 32 + f * 16 + lane15;
                int sA = (kk * 4 + quad) ^ (mA & 15);
                af[f] = *(const short8*)(As + mA * 128 + sA * 8);
            }
#pragma unroll
            for (int f = 0; f < 4; ++f) {
                int nB = wx * 64 + f * 16 + lane15;
                int sB = (kk * 4 + quad) ^ (nB & 15);
                bf[f] = *(const short8*)(Bs + nB * 128 + sB * 8);
            }
#pragma unroll
            for (int fy = 0; fy < 2; ++fy)
#pragma unroll
                for (int fx = 0; fx < 4; ++fx)
                    acc[fy][fx] = __builtin_amdgcn_mfma_f32_16x16x32_bf16(
                        af[fy], bf[fx], acc[fy][fx], 0, 0, 0);
        }

        // epilogue slice: col = nb*128 + ..., C/D layout col=lane&15, row=quad*4+reg
#pragma unroll
        for (int fy = 0; fy < 2; ++fy) {
            int rowb = m0 + wy * 32 + fy * 16 + quad * 4;
#pragma unroll
            for (int fx = 0; fx < 4; ++fx) {
                int col = nb * 128 + wx * 64 + fx * 16 + lane15;
                float bia = bias[col];
                f32x4 v = acc[fy][fx];
#pragma unroll
                for (int r = 0; r < 4; ++r) {
                    int row = rowb + r;
                    if (row < NN)
                        C[(size_t)row * F1 + col] = f2bf(fmaxf(v[r] + bia, 0.0f));
                }
            }
        }
        if (nb < 3) __syncthreads();               // protect Bs before next staging
    }
}

// ========= gemm2: K=512 dbuf bf16 MFMA GEMM, rowscale = rsqrt(cnt+1) =========
// 64x128 tile, BK=32, double-buffered LDS, post-barrier prefetch.
__global__ __launch_bounds__(256) void k_gemm_bf16(
        const unsigned short* __restrict__ A, int lda,
        const unsigned short* __restrict__ Bt, int ldb,
        unsigned short* __restrict__ C, int ldc,
        const int* __restrict__ cnt,
        int M, int K)
{
    __shared__ unsigned short As[2][64 * 32];    // 2 x 4 KB
    __shared__ unsigned short Bs[2][128 * 32];   // 2 x 8 KB

    const int tid = threadIdx.x;
    const int wv = tid >> 6, ln = tid & 63;
    const int m0 = blockIdx.y * 64, n0 = blockIdx.x * 128;
    const int wy = wv >> 1, wx = wv & 1;
    const int lane15 = ln & 15, quad = ln >> 4;

    const int cA = tid, mA_ = cA >> 2, qA = cA & 3;
    const int gqA = qA ^ ((mA_ >> 1) & 3);
    int arow = m0 + mA_; if (arow > M - 1) arow = M - 1;
    const unsigned short* agp = A + (size_t)arow * lda + gqA * 8;
    const int aofs = wv * 512;

    const unsigned short* bgp[2];
    int bofs[2];
#pragma unroll
    for (int i = 0; i < 2; ++i) {
        int c = (i * 4 + wv) * 64 + ln;
        int m = c >> 2, q = c & 3;
        int gq = q ^ ((m >> 1) & 3);
        bgp[i] = Bt + (size_t)(n0 + m) * ldb + gq * 8;
        bofs[i] = (i * 4 + wv) * 512;
    }

    f32x4 acc[2][4];
#pragma unroll
    for (int fy = 0; fy < 2; ++fy)
#pragma unroll
        for (int fx = 0; fx < 4; ++fx)
            acc[fy][fx] = (f32x4)0.0f;

    const int NK = K >> 5;

    __builtin_amdgcn_global_load_lds(
        (const __attribute__((address_space(1))) void*)agp,
        (__attribute__((address_space(3))) void*)(&As[0][0] + aofs), 16, 0, 0);
#pragma unroll
    for (int i = 0; i < 2; ++i)
        __builtin_amdgcn_global_load_lds(
            (const __attribute__((address_space(1))) void*)bgp[i],
            (__attribute__((address_space(3))) void*)(&Bs[0][0] + bofs[i]), 16, 0, 0);

    for (int ks = 0; ks < NK; ++ks) {
        __syncthreads();
        if (ks + 1 < NK) {
            int ko = (ks + 1) << 5;
            int nb = (ks + 1) & 1;
            __builtin_amdgcn_global_load_lds(
                (const __attribute__((address_space(1))) void*)(agp + ko),
                (__attribute__((address_space(3))) void*)(&As[nb][0] + aofs), 16, 0, 0);
#pragma unroll
            for (int i = 0; i < 2; ++i)
                __builtin_amdgcn_global_load_lds(
                    (const __attribute__((address_space(1))) void*)(bgp[i] + ko),
                    (__attribute__((address_space(3))) void*)(&Bs[nb][0] + bofs[i]), 16, 0, 0);
        }
        const int b = ks & 1;
        short8 af[2], bf[4];
#pragma unroll
        for (int f = 0; f < 2; ++f) {
            int mA = wy * 32 + f * 16 + lane15;
            int sA = quad ^ ((mA >> 1) & 3);
            af[f] = *(const short8*)(&As[b][0] + mA * 32 + sA * 8);
        }
#pragma unroll
        for (int f = 0; f < 4; ++f) {
            int nB = wx * 64 + f * 16 + lane15;
            int sB = quad ^ ((nB >> 1) & 3);
            bf[f] = *(const short8*)(&Bs[b][0] + nB * 32 + sB * 8);
        }
#pragma unroll
        for (int fy = 0; fy < 2; ++fy)
#pragma unroll
            for (int fx = 0; fx < 4; ++fx)
                acc[fy][fx] = __builtin_amdgcn_mfma_f32_16x16x32_bf16(
                    af[fy], bf[fx], acc[fy][fx], 0, 0, 0);
    }

#pragma unroll
    for (int fy = 0; fy < 2; ++fy) {
        int rowb = m0 + wy * 32 + fy * 16 + quad * 4;
        float rs[4];
#pragma unroll
        for (int r = 0; r < 4; ++r) {
            int row = rowb + r; if (row > M - 1) row = M - 1;
            rs[r] = rsqrtf((float)cnt[row] + 1.0f);
        }
#pragma unroll
        for (int fx = 0; fx < 4; ++fx) {
            int col = n0 + wx * 64 + fx * 16 + lane15;
            f32x4 v = acc[fy][fx];
#pragma unroll
            for (int r = 0; r < 4; ++r) {
                int row = rowb + r;
                if (row < M)
                    C[(size_t)row * ldc + col] = f2bf(v[r] * rs[r]);
            }
        }
    }
}

// ========= gather2: out[n] = relu( dn*( t2s[n] + sum t2s[s] ) + b2 ) =========
// t2s rows pre-scaled by dinv[row] in gemm2's epilogue. 1 node / wave.
__global__ __launch_bounds__(256) void k_gather2(
        const ushort4* __restrict__ t4, const int* __restrict__ slot,
        const int* __restrict__ cnt, const float* __restrict__ b2,
        float* __restrict__ out) {
    int n = blockIdx.x * 4 + (threadIdx.x >> 6);
    int c = threadIdx.x & 63;                     // 4 bf16 per lane over 256 cols
    if (n >= NN) return;
    int deg = cnt[n]; if (deg > SLOT) deg = SLOT;
    float dn = rsqrtf((float)deg + 1.0f);
    const int* sl = slot + n * SLOT;
    ushort4 a = t4[(size_t)n * 64 + c];
    float sx = bf2f(a.x), sy = bf2f(a.y), sz = bf2f(a.z), sw = bf2f(a.w);
    int j = 0;
    for (; j + 8 <= deg; j += 8) {
        int i0 = sl[j],     i1 = sl[j + 1], i2 = sl[j + 2], i3 = sl[j + 3];
        int i4 = sl[j + 4], i5 = sl[j + 5], i6 = sl[j + 6], i7 = sl[j + 7];
        ushort4 v0 = t4[(size_t)i0 * 64 + c];
        ushort4 v1 = t4[(size_t)i1 * 64 + c];
        ushort4 v2 = t4[(size_t)i2 * 64 + c];
        ushort4 v3 = t4[(size_t)i3 * 64 + c];
        ushort4 v4 = t4[(size_t)i4 * 64 + c];
        ushort4 v5 = t4[(size_t)i5 * 64 + c];
        ushort4 v6 = t4[(size_t)i6 * 64 + c];
        ushort4 v7 = t4[(size_t)i7 * 64 + c];
        sx += bf2f(v0.x) + bf2f(v1.x) + bf2f(v2.x) + bf2f(v3.x)
            + bf2f(v4.x) + bf2f(v5.x) + bf2f(v6.x) + bf2f(v7.x);
        sy += bf2f(v0.y) + bf2f(v1.y) + bf2f(v2.y) + bf2f(v3.y)
            + bf2f(v4.y) + bf2f(v5.y) + bf2f(v6.y) + bf2f(v7.y);
        sz += bf2f(v0.z) + bf2f(v1.z) + bf2f(v2.z) + bf2f(v3.z)
            + bf2f(v4.z) + bf2f(v5.z) + bf2f(v6.z) + bf2f(v7.z);
        sw += bf2f(v0.w) + bf2f(v1.w) + bf2f(v2.w) + bf2f(v3.w)
            + bf2f(v4.w) + bf2f(v5.w) + bf2f(v6.w) + bf2f(v7.w);
    }
    for (; j + 4 <= deg; j += 4) {
        int i0 = sl[j], i1 = sl[j + 1], i2 = sl[j + 2], i3 = sl[j + 3];
        ushort4 v0 = t4[(size_t)i0 * 64 + c];
        ushort4 v1 = t4[(size_t)i1 * 64 + c];
        ushort4 v2 = t4[(size_t)i2 * 64 + c];
        ushort4 v3 = t4[(size_t)i3 * 64 + c];
        sx += bf2f(v0.x) + bf2f(v1.x) + bf2f(v2.x) + bf2f(v3.x);
        sy += bf2f(v0.y) + bf2f(v1.y) + bf2f(v2.y) + bf2f(v3.y);
        sz += bf2f(v0.z) + bf2f(v1.z) + bf2f(v2.z) + bf2f(v3.z);
        sw += bf2f(v0.w) + bf2f(v1.w) + bf2f(v2.w) + bf2f(v3.w);
    }
    for (; j < deg; ++j) {
        ushort4 v = t4[(size_t)sl[j] * 64 + c];
        sx += bf2f(v.x); sy += bf2f(v.y); sz += bf2f(v.z); sw += bf2f(v.w);
    }
    int f = c * 4;
    float* o = out + (size_t)n * F2;
    if (f     < F2) o[f]     = fmaxf(dn * sx + b2[f],     0.f);
    if (f + 1 < F2) o[f + 1] = fmaxf(dn * sy + b2[f + 1], 0.f);
    if (f + 2 < F2) o[f + 2] = fmaxf(dn * sz + b2[f + 2], 0.f);
    if (f + 3 < F2) o[f + 3] = fmaxf(dn * sw + b2[f + 3], 0.f);
}

extern "C" void kernel_launch(void* const* d_in, const int* in_sizes, int n_in,
                              void* d_out, int out_size, void* d_ws, size_t ws_size,
                              hipStream_t stream) {
    const float* x  = (const float*)d_in[0];
    const int*   ei = (const int*)d_in[1];     // [2, NE]: first NE = src, next NE = dst
    const float* W1 = (const float*)d_in[2];
    const float* b1 = (const float*)d_in[3];
    const float* W2 = (const float*)d_in[4];
    const float* b2 = (const float*)d_in[5];
    float* out = (float*)d_out;

    // workspace carve (256 B aligned)
    char* p = (char*)d_ws;
    auto carve = [&](size_t bytes) { char* r = p; p += (bytes + 255) & ~(size_t)255; return r; };
    int*            cnt  = (int*)carve(NN * 4);
    int*            slot = (int*)carve((size_t)NN * SLOT * 4);
    unsigned short* xs   = (unsigned short*)carve((size_t)NN * F0 * 2);
    unsigned short* h1   = (unsigned short*)carve((size_t)NN * F1 * 2);
    unsigned short* t2s  = (unsigned short*)carve((size_t)NN * 256 * 2);
    unsigned short* w1t  = (unsigned short*)carve((size_t)F1 * F0 * 2);
    unsigned short* w2t  = (unsigned short*)carve((size_t)256 * F1 * 2);

    // 1) zero degree counters
    hipMemsetAsync(cnt, 0, NN * sizeof(int), stream);
    // 2) fused hist+bucket CSR build
    k_build<<<(NE / 4 + 255) / 256, 256, 0, stream>>>(
        (const int4*)ei, (const int4*)(ei + NE), cnt, slot);
    // 3) fused prep: xs = bf16(dinv*x), W1t, W2t
    k_prep<<<6250 + 256 + 512, 256, 0, stream>>>(
        (const float4*)x, cnt, (ushort4*)xs, W1, w1t, W2, w2t);
    // 4) fused layer 1: gather(into LDS) + K=128 MFMA GEMM + bias + relu -> h1
    k_fused1<<<MT64, 256, 0, stream>>>((const unsigned int*)xs, slot, cnt, w1t, b1, h1);
    // 5) layer 2 GEMM (rowscale=dinv on the fly) -> t2s
    k_gemm_bf16<<<dim3(256 / 128, MT64), 256, 0, stream>>>(
        h1, F1, w2t, F1, t2s, 256, cnt, NN, F1);
    // 6) gather2 + bias + relu -> out
    k_gather2<<<(NN + 3) / 4, 256, 0, stream>>>((const ushort4*)t2s, slot, cnt, b2, out);
}

// Round 9
// 238.716 us; speedup vs baseline: 1.1779x; 1.1779x over previous
//
#include <hip/hip_runtime.h>

// Problem constants
constexpr int NN  = 50000;   // nodes
constexpr int NE  = 400000;  // edges
constexpr int F0  = 128;     // input features
constexpr int F1  = 512;     // hidden features
constexpr int F2  = 250;     // output features
constexpr int MT64 = 782;    // M tiles of 64 (782*64 = 50048)
constexpr int SLOT = 64;     // fixed-capacity CSR stride (Poisson(8): P(deg>64)~1e-40)

typedef short  short8 __attribute__((ext_vector_type(8)));
typedef float  f32x4  __attribute__((ext_vector_type(4)));

__device__ inline unsigned short f2bf(float f) {
    union { float f; unsigned u; } v; v.f = f;
    unsigned u = v.u;
    return (unsigned short)((u + 0x7FFFu + ((u >> 16) & 1u)) >> 16);   // RNE
}
__device__ inline float bf2f(unsigned short h) {
    union { unsigned u; float f; } v; v.u = ((unsigned)h) << 16;
    return v.f;
}
__device__ inline float bflo(unsigned u) {
    union { unsigned u; float f; } v; v.u = u << 16; return v.f;
}
__device__ inline float bfhi(unsigned u) {
    union { unsigned u; float f; } v; v.u = u & 0xFFFF0000u; return v.f;
}

// ========= CSR build: fused hist+bucket into fixed-stride slots =========
__global__ void k_build(const int4* __restrict__ src4, const int4* __restrict__ dst4,
                        int* __restrict__ cnt, int* __restrict__ slot) {
    int t = blockIdx.x * 256 + threadIdx.x;        // NE/4
    if (t >= NE / 4) return;
    int4 s = src4[t];
    int4 d = dst4[t];
    int p;
    p = atomicAdd(&cnt[d.x], 1); if (p < SLOT) slot[d.x * SLOT + p] = s.x;
    p = atomicAdd(&cnt[d.y], 1); if (p < SLOT) slot[d.y * SLOT + p] = s.y;
    p = atomicAdd(&cnt[d.z], 1); if (p < SLOT) slot[d.z * SLOT + p] = s.z;
    p = atomicAdd(&cnt[d.w], 1); if (p < SLOT) slot[d.w * SLOT + p] = s.w;
}

// ========= fused prep: xs = bf16(rsqrt(cnt+1)*x), W1t, W2t =========
__global__ __launch_bounds__(256) void k_prep(
        const float4* __restrict__ x4, const int* __restrict__ cnt,
        ushort4* __restrict__ xs,
        const float* __restrict__ W1, unsigned short* __restrict__ w1t,
        const float* __restrict__ W2, unsigned short* __restrict__ w2t) {
    int b = blockIdx.x;
    if (b < 6250) {                                // NN*32 = 1,600,000 float4s
        int t = b * 256 + threadIdx.x;
        float dn = rsqrtf((float)cnt[t >> 5] + 1.0f);
        float4 v = x4[t];
        ushort4 o;
        o.x = f2bf(dn * v.x); o.y = f2bf(dn * v.y);
        o.z = f2bf(dn * v.z); o.w = f2bf(dn * v.w);
        xs[t] = o;
    } else if (b < 6250 + 256) {                   // W1 [128,512] -> [512,128]
        int t = (b - 6250) * 256 + threadIdx.x;
        int n = t >> 7, k = t & 127;
        w1t[t] = f2bf(W1[k * F1 + n]);
    } else {                                       // W2 [512,250] -> [256,512], pad
        int t = (b - 6506) * 256 + threadIdx.x;
        int n = t >> 9, k = t & 511;
        w2t[t] = (n < F2) ? f2bf(W2[k * F2 + n]) : (unsigned short)0;
    }
}

// ========= gather1: agg1[n] = bf16( dn * ( xs[n] + sum xs[s] ) ), 1 node/wave =========
__global__ __launch_bounds__(256) void k_gather1(
        const unsigned int* __restrict__ xs, const int* __restrict__ slot,
        const int* __restrict__ cnt, unsigned int* __restrict__ agg) {
    int n = blockIdx.x * 4 + (threadIdx.x >> 6);   // 4 waves / block, 1 node / wave
    int c = threadIdx.x & 63;                      // uint column (2 bf16)
    if (n >= NN) return;
    int deg = cnt[n]; if (deg > SLOT) deg = SLOT;
    float dn = rsqrtf((float)deg + 1.0f);
    const int* sl = slot + n * SLOT;
    unsigned a = xs[(size_t)n * 64 + c];
    float s0 = bflo(a), s1 = bfhi(a);
    int j = 0;
    for (; j + 8 <= deg; j += 8) {
        int i0 = sl[j],     i1 = sl[j + 1], i2 = sl[j + 2], i3 = sl[j + 3];
        int i4 = sl[j + 4], i5 = sl[j + 5], i6 = sl[j + 6], i7 = sl[j + 7];
        unsigned v0 = xs[(size_t)i0 * 64 + c];
        unsigned v1 = xs[(size_t)i1 * 64 + c];
        unsigned v2 = xs[(size_t)i2 * 64 + c];
        unsigned v3 = xs[(size_t)i3 * 64 + c];
        unsigned v4 = xs[(size_t)i4 * 64 + c];
        unsigned v5 = xs[(size_t)i5 * 64 + c];
        unsigned v6 = xs[(size_t)i6 * 64 + c];
        unsigned v7 = xs[(size_t)i7 * 64 + c];
        s0 += bflo(v0) + bflo(v1) + bflo(v2) + bflo(v3)
            + bflo(v4) + bflo(v5) + bflo(v6) + bflo(v7);
        s1 += bfhi(v0) + bfhi(v1) + bfhi(v2) + bfhi(v3)
            + bfhi(v4) + bfhi(v5) + bfhi(v6) + bfhi(v7);
    }
    for (; j + 4 <= deg; j += 4) {
        int i0 = sl[j], i1 = sl[j + 1], i2 = sl[j + 2], i3 = sl[j + 3];
        unsigned v0 = xs[(size_t)i0 * 64 + c];
        unsigned v1 = xs[(size_t)i1 * 64 + c];
        unsigned v2 = xs[(size_t)i2 * 64 + c];
        unsigned v3 = xs[(size_t)i3 * 64 + c];
        s0 += bflo(v0) + bflo(v1) + bflo(v2) + bflo(v3);
        s1 += bfhi(v0) + bfhi(v1) + bfhi(v2) + bfhi(v3);
    }
    for (; j < deg; ++j) {
        unsigned v = xs[(size_t)sl[j] * 64 + c];
        s0 += bflo(v); s1 += bfhi(v);
    }
    agg[(size_t)n * 64 + c] =
        (unsigned)f2bf(dn * s0) | ((unsigned)f2bf(dn * s1) << 16);
}

// ========= gemm1: single-shot K=128 bf16 MFMA GEMM (+bias+relu) =========
// C[M,512] = A[M,128] * Bt[512,128]^T. 64x128 tile, whole K in LDS, ONE barrier.
// 16-slot XOR swizzle: chunk q of row m holds global chunk q^(m&15).
__global__ __launch_bounds__(256) void k_gemm1(
        const unsigned short* __restrict__ A,
        const unsigned short* __restrict__ Bt,
        unsigned short* __restrict__ C,
        const float* __restrict__ bias, int M)
{
    __shared__ unsigned short As[64 * 128];    // 16 KB
    __shared__ unsigned short Bs[128 * 128];   // 32 KB

    const int tid = threadIdx.x;
    const int wv = tid >> 6, ln = tid & 63;
    const int m0 = blockIdx.y * 64, n0 = blockIdx.x * 128;
    const int wy = wv >> 1, wx = wv & 1;
    const int lane15 = ln & 15, quad = ln >> 4;

#pragma unroll
    for (int i = 0; i < 4; ++i) {              // A: 1024 chunks
        int c = i * 256 + tid;
        int m = c >> 4, q = c & 15;
        int gq = q ^ (m & 15);
        int arow = m0 + m; if (arow > M - 1) arow = M - 1;
        __builtin_amdgcn_global_load_lds(
            (const __attribute__((address_space(1))) void*)(A + (size_t)arow * 128 + gq * 8),
            (__attribute__((address_space(3))) void*)(As + (i * 4 + wv) * 512), 16, 0, 0);
    }
#pragma unroll
    for (int i = 0; i < 8; ++i) {              // B: 2048 chunks
        int c = i * 256 + tid;
        int n = c >> 4, q = c & 15;
        int gq = q ^ (n & 15);
        __builtin_amdgcn_global_load_lds(
            (const __attribute__((address_space(1))) void*)(Bt + (size_t)(n0 + n) * 128 + gq * 8),
            (__attribute__((address_space(3))) void*)(Bs + (i * 4 + wv) * 512), 16, 0, 0);
    }

    f32x4 acc[2][4];
#pragma unroll
    for (int fy = 0; fy < 2; ++fy)
#pragma unroll
        for (int fx = 0; fx < 4; ++fx)
            acc[fy][fx] = (f32x4)0.0f;

    __syncthreads();                             // the only barrier

#pragma unroll
    for (int kk = 0; kk < 4; ++kk) {             // K = 4 x 32
        short8 af[2], bf[4];
#pragma unroll
        for (int f = 0; f < 2; ++f) {
            int mA = wy * 32 + f * 16 + lane15;
            int sA = (kk * 4 + quad) ^ (mA & 15);
            af[f] = *(const short8*)(As + mA * 128 + sA * 8);
        }
#pragma unroll
        for (int f = 0; f < 4; ++f) {
            int nB = wx * 64 + f * 16 + lane15;
            int sB = (kk * 4 + quad) ^ (nB & 15);
            bf[f] = *(const short8*)(Bs + nB * 128 + sB * 8);
        }
#pragma unroll
        for (int fy = 0; fy < 2; ++fy)
#pragma unroll
            for (int fx = 0; fx < 4; ++fx)
                acc[fy][fx] = __builtin_amdgcn_mfma_f32_16x16x32_bf16(
                    af[fy], bf[fx], acc[fy][fx], 0, 0, 0);
    }

#pragma unroll
    for (int fy = 0; fy < 2; ++fy) {
        int rowb = m0 + wy * 32 + fy * 16 + quad * 4;
#pragma unroll
        for (int fx = 0; fx < 4; ++fx) {
            int col = n0 + wx * 64 + fx * 16 + lane15;
            float bia = bias[col];
            f32x4 v = acc[fy][fx];
#pragma unroll
            for (int r = 0; r < 4; ++r) {
                int row = rowb + r;
                if (row < M)
                    C[(size_t)row * F1 + col] = f2bf(fmaxf(v[r] + bia, 0.0f));
            }
        }
    }
}

// ========= gemm2: 64x256 (full-N) K=512 dbuf bf16 MFMA GEMM, rowscale =========
// Each block: all 256 output cols for 64 rows -> W2t staged ONCE per block,
// 16 MFMA per wave per barrier. LDS 2*(4+16)=40KB -> 4 blocks/CU.
__global__ __launch_bounds__(256) void k_gemm2(
        const unsigned short* __restrict__ A,    // h1 [M,512]
        const unsigned short* __restrict__ Bt,   // w2t [256,512]
        unsigned short* __restrict__ C,          // t2s [M,256]
        const int* __restrict__ cnt, int M)
{
    __shared__ unsigned short As[2][64 * 32];    // 2 x 4 KB
    __shared__ unsigned short Bs[2][256 * 32];   // 2 x 16 KB

    const int tid = threadIdx.x;
    const int wv = tid >> 6, ln = tid & 63;
    const int m0 = blockIdx.x * 64;
    const int wy = wv >> 1, wx = wv & 1;         // 2x2 waves: 32 rows x 128 cols each
    const int lane15 = ln & 15, quad = ln >> 4;

    // A staging: 256 chunks (64 rows x 4 slots), 1 per thread
    const int mA_ = tid >> 2, qA = tid & 3;
    const int gqA = qA ^ ((mA_ >> 1) & 3);
    int arow = m0 + mA_; if (arow > M - 1) arow = M - 1;
    const unsigned short* agp = A + (size_t)arow * F1 + gqA * 8;
    const int aofs = wv * 512;

    // B staging: 1024 chunks (256 rows x 4 slots), 4 per thread
    const unsigned short* bgp[4];
    int bofs[4];
#pragma unroll
    for (int i = 0; i < 4; ++i) {
        int c = (i * 4 + wv) * 64 + ln;
        int n = c >> 2, q = c & 3;
        int gq = q ^ ((n >> 1) & 3);
        bgp[i] = Bt + (size_t)n * F1 + gq * 8;
        bofs[i] = (i * 4 + wv) * 512;
    }

    f32x4 acc[2][8];
#pragma unroll
    for (int fy = 0; fy < 2; ++fy)
#pragma unroll
        for (int fx = 0; fx < 8; ++fx)
            acc[fy][fx] = (f32x4)0.0f;

    const int NK = F1 / 32;                      // 16

    __builtin_amdgcn_global_load_lds(
        (const __attribute__((address_space(1))) void*)agp,
        (__attribute__((address_space(3))) void*)(&As[0][0] + aofs), 16, 0, 0);
#pragma unroll
    for (int i = 0; i < 4; ++i)
        __builtin_amdgcn_global_load_lds(
            (const __attribute__((address_space(1))) void*)bgp[i],
            (__attribute__((address_space(3))) void*)(&Bs[0][0] + bofs[i]), 16, 0, 0);

    for (int ks = 0; ks < NK; ++ks) {
        __syncthreads();
        if (ks + 1 < NK) {
            int ko = (ks + 1) << 5;
            int nb = (ks + 1) & 1;
            __builtin_amdgcn_global_load_lds(
                (const __attribute__((address_space(1))) void*)(agp + ko),
                (__attribute__((address_space(3))) void*)(&As[nb][0] + aofs), 16, 0, 0);
#pragma unroll
            for (int i = 0; i < 4; ++i)
                __builtin_amdgcn_global_load_lds(
                    (const __attribute__((address_space(1))) void*)(bgp[i] + ko),
                    (__attribute__((address_space(3))) void*)(&Bs[nb][0] + bofs[i]), 16, 0, 0);
        }
        const int b = ks & 1;
        short8 af[2], bf[8];
#pragma unroll
        for (int f = 0; f < 2; ++f) {
            int mA = wy * 32 + f * 16 + lane15;
            int sA = quad ^ ((mA >> 1) & 3);
            af[f] = *(const short8*)(&As[b][0] + mA * 32 + sA * 8);
        }
#pragma unroll
        for (int f = 0; f < 8; ++f) {
            int nB = wx * 128 + f * 16 + lane15;
            int sB = quad ^ ((nB >> 1) & 3);
            bf[f] = *(const short8*)(&Bs[b][0] + nB * 32 + sB * 8);
        }
#pragma unroll
        for (int fy = 0; fy < 2; ++fy)
#pragma unroll
            for (int fx = 0; fx < 8; ++fx)
                acc[fy][fx] = __builtin_amdgcn_mfma_f32_16x16x32_bf16(
                    af[fy], bf[fx], acc[fy][fx], 0, 0, 0);
    }

#pragma unroll
    for (int fy = 0; fy < 2; ++fy) {
        int rowb = m0 + wy * 32 + fy * 16 + quad * 4;
        float rs[4];
#pragma unroll
        for (int r = 0; r < 4; ++r) {
            int row = rowb + r; if (row > M - 1) row = M - 1;
            rs[r] = rsqrtf((float)cnt[row] + 1.0f);
        }
#pragma unroll
        for (int fx = 0; fx < 8; ++fx) {
            int col = wx * 128 + fx * 16 + lane15;
            f32x4 v = acc[fy][fx];
#pragma unroll
            for (int r = 0; r < 4; ++r) {
                int row = rowb + r;
                if (row < M)
                    C[(size_t)row * 256 + col] = f2bf(v[r] * rs[r]);
            }
        }
    }
}

// ========= gather2: out[n] = relu( dn*( t2s[n] + sum t2s[s] ) + b2 ) =========
__global__ __launch_bounds__(256) void k_gather2(
        const ushort4* __restrict__ t4, const int* __restrict__ slot,
        const int* __restrict__ cnt, const float* __restrict__ b2,
        float* __restrict__ out) {
    int n = blockIdx.x * 4 + (threadIdx.x >> 6);
    int c = threadIdx.x & 63;                     // 4 bf16 per lane over 256 cols
    if (n >= NN) return;
    int deg = cnt[n]; if (deg > SLOT) deg = SLOT;
    float dn = rsqrtf((float)deg + 1.0f);
    const int* sl = slot + n * SLOT;
    ushort4 a = t4[(size_t)n * 64 + c];
    float sx = bf2f(a.x), sy = bf2f(a.y), sz = bf2f(a.z), sw = bf2f(a.w);
    int j = 0;
    for (; j + 8 <= deg; j += 8) {
        int i0 = sl[j],     i1 = sl[j + 1], i2 = sl[j + 2], i3 = sl[j + 3];
        int i4 = sl[j + 4], i5 = sl[j + 5], i6 = sl[j + 6], i7 = sl[j + 7];
        ushort4 v0 = t4[(size_t)i0 * 64 + c];
        ushort4 v1 = t4[(size_t)i1 * 64 + c];
        ushort4 v2 = t4[(size_t)i2 * 64 + c];
        ushort4 v3 = t4[(size_t)i3 * 64 + c];
        ushort4 v4 = t4[(size_t)i4 * 64 + c];
        ushort4 v5 = t4[(size_t)i5 * 64 + c];
        ushort4 v6 = t4[(size_t)i6 * 64 + c];
        ushort4 v7 = t4[(size_t)i7 * 64 + c];
        sx += bf2f(v0.x) + bf2f(v1.x) + bf2f(v2.x) + bf2f(v3.x)
            + bf2f(v4.x) + bf2f(v5.x) + bf2f(v6.x) + bf2f(v7.x);
        sy += bf2f(v0.y) + bf2f(v1.y) + bf2f(v2.y) + bf2f(v3.y)
            + bf2f(v4.y) + bf2f(v5.y) + bf2f(v6.y) + bf2f(v7.y);
        sz += bf2f(v0.z) + bf2f(v1.z) + bf2f(v2.z) + bf2f(v3.z)
            + bf2f(v4.z) + bf2f(v5.z) + bf2f(v6.z) + bf2f(v7.z);
        sw += bf2f(v0.w) + bf2f(v1.w) + bf2f(v2.w) + bf2f(v3.w)
            + bf2f(v4.w) + bf2f(v5.w) + bf2f(v6.w) + bf2f(v7.w);
    }
    for (; j + 4 <= deg; j += 4) {
        int i0 = sl[j], i1 = sl[j + 1], i2 = sl[j + 2], i3 = sl[j + 3];
        ushort4 v0 = t4[(size_t)i0 * 64 + c];
        ushort4 v1 = t4[(size_t)i1 * 64 + c];
        ushort4 v2 = t4[(size_t)i2 * 64 + c];
        ushort4 v3 = t4[(size_t)i3 * 64 + c];
        sx += bf2f(v0.x) + bf2f(v1.x) + bf2f(v2.x) + bf2f(v3.x);
        sy += bf2f(v0.y) + bf2f(v1.y) + bf2f(v2.y) + bf2f(v3.y);
        sz += bf2f(v0.z) + bf2f(v1.z) + bf2f(v2.z) + bf2f(v3.z);
        sw += bf2f(v0.w) + bf2f(v1.w) + bf2f(v2.w) + bf2f(v3.w);
    }
    for (; j < deg; ++j) {
        ushort4 v = t4[(size_t)sl[j] * 64 + c];
        sx += bf2f(v.x); sy += bf2f(v.y); sz += bf2f(v.z); sw += bf2f(v.w);
    }
    int f = c * 4;
    float* o = out + (size_t)n * F2;
    if (f     < F2) o[f]     = fmaxf(dn * sx + b2[f],     0.f);
    if (f + 1 < F2) o[f + 1] = fmaxf(dn * sy + b2[f + 1], 0.f);
    if (f + 2 < F2) o[f + 2] = fmaxf(dn * sz + b2[f + 2], 0.f);
    if (f + 3 < F2) o[f + 3] = fmaxf(dn * sw + b2[f + 3], 0.f);
}

extern "C" void kernel_launch(void* const* d_in, const int* in_sizes, int n_in,
                              void* d_out, int out_size, void* d_ws, size_t ws_size,
                              hipStream_t stream) {
    const float* x  = (const float*)d_in[0];
    const int*   ei = (const int*)d_in[1];     // [2, NE]: first NE = src, next NE = dst
    const float* W1 = (const float*)d_in[2];
    const float* b1 = (const float*)d_in[3];
    const float* W2 = (const float*)d_in[4];
    const float* b2 = (const float*)d_in[5];
    float* out = (float*)d_out;

    // workspace carve (256 B aligned)
    char* p = (char*)d_ws;
    auto carve = [&](size_t bytes) { char* r = p; p += (bytes + 255) & ~(size_t)255; return r; };
    int*            cnt  = (int*)carve(NN * 4);
    int*            slot = (int*)carve((size_t)NN * SLOT * 4);
    unsigned short* xs   = (unsigned short*)carve((size_t)NN * F0 * 2);
    unsigned short* agg1 = (unsigned short*)carve((size_t)NN * F0 * 2);
    unsigned short* h1   = (unsigned short*)carve((size_t)NN * F1 * 2);
    unsigned short* t2s  = (unsigned short*)carve((size_t)NN * 256 * 2);
    unsigned short* w1t  = (unsigned short*)carve((size_t)F1 * F0 * 2);
    unsigned short* w2t  = (unsigned short*)carve((size_t)256 * F1 * 2);

    // 1) zero degree counters
    hipMemsetAsync(cnt, 0, NN * sizeof(int), stream);
    // 2) fused hist+bucket CSR build (fixed stride)
    k_build<<<(NE / 4 + 255) / 256, 256, 0, stream>>>(
        (const int4*)ei, (const int4*)(ei + NE), cnt, slot);
    // 3) fused prep: xs = bf16(dinv*x), W1t, W2t
    k_prep<<<6250 + 256 + 512, 256, 0, stream>>>(
        (const float4*)x, cnt, (ushort4*)xs, W1, w1t, W2, w2t);
    // 4) layer 1 aggregate (wave-per-node, high TLP)
    k_gather1<<<(NN + 3) / 4, 256, 0, stream>>>((const unsigned int*)xs, slot, cnt,
                                                (unsigned int*)agg1);
    // 5) layer 1 GEMM: single-shot K=128, one barrier
    k_gemm1<<<dim3(F1 / 128, MT64), 256, 0, stream>>>(agg1, w1t, h1, b1, NN);
    // 6) layer 2 GEMM: 64x256 full-N tile, rowscale -> t2s
    k_gemm2<<<MT64, 256, 0, stream>>>(h1, w2t, t2s, cnt, NN);
    // 7) gather2 + bias + relu -> out
    k_gather2<<<(NN + 3) / 4, 256, 0, stream>>>((const ushort4*)t2s, slot, cnt, b2, out);
}